// Round 3
// 176.371 us; speedup vs baseline: 1.3864x; 1.3864x over previous
//
#include <hip/hip_runtime.h>
#include <math.h>

// R3: FFT + branch-cut patch with BIT-EXACT v5 summation order.
// R2 lesson: patch targeted the right set (flips require |i_fft+eps| <=
// FFT-err ~5e-4 << TAU, so flipped points always enter the patch), but the
// recompute used a nested-reversed fmaf order (w3*x3 first within each
// quad) -> a different rounding coin than v5 -> fresh 2pi flips. v5 passed
// with SEQUENTIAL-k fmaf (k=0..399, acc from 0); IEEE fmaf is deterministic
// and hipcc without fast-math cannot reassociate an explicit fmaf chain, so
// reproducing that order makes patched outputs bit-identical to v5's.
// f=256 is structurally flip-free (W row 513 ~ 1e-13 -> |i| << eps).
// Structure unchanged: per block 16 frames, 256 thr, 3 blocks/CU:
//   stage xs/win/tw -> pack real512->cplx256 bit-reversed -> 8 radix-2 DIT
//   stages in LDS -> real-FFT unpack in place -> fused mag/phase + direct
//   coalesced store; risky set (|i+eps|<TAU && r+eps<TAU) recomputed via
//   sequential direct conv on a cold divergent path (~2 pts/block).

#define BATCH 16
#define NSAMP 160000
#define NF 257
#define NT 1603
#define KLEN 400
#define INC 100
#define PADL 300
#define EPSF 1.1920928955078125e-7f
#define TAU 1e-2f

#define FPB 16                            // frames per block
#define ZSTR 258                          // complex stride per frame (+2 pad)
#define XSPAN ((FPB - 1) * INC + KLEN)    // 1900
#define NTB ((NT + FPB - 1) / FPB)        // 101

__global__ __launch_bounds__(256, 3)
void stft_fft(const float* __restrict__ x, const float* __restrict__ w,
              float* __restrict__ out) {
  __shared__ float2 Z[FPB * ZSTR];        // 33024 B: packed/FFT/Y data
  __shared__ float2 tw[256];              // e^{-2*pi*i*j/512}, j=0..255
  __shared__ float y256[FPB];             // Y[256] (real) per frame
  __shared__ __align__(16) float xs[XSPAN];  // zero-padded input window
  __shared__ __align__(16) float win[KLEN];  // = W row 0 exactly

  const int tid = threadIdx.x;
  const int t0 = blockIdx.x * FPB;
  const int b = blockIdx.y;
  const int tl = tid & 15;                // frame index (frame-minor map)
  const int th = tid >> 4;                // 0..15

  // ---- stage x window (vectorized, zero-padded), window row, twiddles ----
  const long xb = (long)b * NSAMP;
  const int base = t0 * INC - PADL;
  for (int r = 0; r < 2; ++r) {
    int i4 = r * 256 + tid;
    if (4 * i4 < XSPAN) {
      int g = base + 4 * i4;
      float4 v;
      if (g >= 0 && g + 3 < NSAMP) {
        v = *(const float4*)(x + xb + g);
      } else {
        v.x = (g + 0 >= 0 && g + 0 < NSAMP) ? x[xb + g + 0] : 0.f;
        v.y = (g + 1 >= 0 && g + 1 < NSAMP) ? x[xb + g + 1] : 0.f;
        v.z = (g + 2 >= 0 && g + 2 < NSAMP) ? x[xb + g + 2] : 0.f;
        v.w = (g + 3 >= 0 && g + 3 < NSAMP) ? x[xb + g + 3] : 0.f;
      }
      *(float4*)&xs[4 * i4] = v;
    }
  }
  if (tid < KLEN / 4) {                   // W[0][k] = win[k]*cos(0) = fp32(win)
    *(float4*)&win[4 * tid] = *(const float4*)(w + 4 * tid);
  }
  {
    double a = (double)tid * (6.283185307179586476925286766559 / 512.0);
    tw[tid] = make_float2((float)cos(a), (float)(-sin(a)));
  }
  __syncthreads();

  // ---- window + pack real-512 -> complex-256, bit-reversed positions ----
  for (int r = 0; r < 16; ++r) {
    int m = r * 16 + th;                  // 0..255
    float2 zv = make_float2(0.f, 0.f);
    if (m < 200) {                        // y[n]=0 for n>=400
      float2 xv = *(const float2*)&xs[tl * INC + 2 * m];
      float2 wv = *(const float2*)&win[2 * m];
      zv = make_float2(xv.x * wv.x, xv.y * wv.y);
    }
    int p = __brev((unsigned)m) >> 24;    // bitrev8
    Z[tl * ZSTR + p] = zv;
  }

  // ---- 8 in-place radix-2 DIT stages (bit-reversed in, natural out) ----
  for (int s = 0; s < 8; ++s) {
    __syncthreads();
    const int half = 1 << s;
    for (int r = 0; r < 8; ++r) {
      int j = r * 16 + th;                // butterfly 0..127
      int q = j & (half - 1);
      int i0 = ((j >> s) << (s + 1)) | q;
      float2* Zt = Z + tl * ZSTR;
      float2 a = Zt[i0];
      float2 bb = Zt[i0 + half];
      float2 wv = tw[q << (8 - s)];       // e^{-2*pi*i*q/2^{s+1}}
      float2 bt = make_float2(bb.x * wv.x - bb.y * wv.y,
                              bb.x * wv.y + bb.y * wv.x);
      Zt[i0] = make_float2(a.x + bt.x, a.y + bt.y);
      Zt[i0 + half] = make_float2(a.x - bt.x, a.y - bt.y);
    }
  }
  __syncthreads();

  // ---- real-FFT unpack: Y[p] and Y[256-p] from Z[p], Z[256-p], in place ----
  // Ze=(Z0+conj Z1)/2, Zo=(Z0-conj Z1)/(2i), T=e^{-2pi i p/512}:
  // Y[p]=Ze+T*Zo ; Y[256-p]=conj(Ze-T*Zo). Pair sets are disjoint -> no sync.
  for (int r = 0; r < 9; ++r) {
    int tau = r * 256 + tid;
    if (tau < FPB * 129) {
      int t = tau & 15;
      int p = tau >> 4;                   // 0..128
      float2* Zt = Z + t * ZSTR;
      float2 z0 = Zt[p];
      float2 z1 = Zt[(256 - p) & 255];
      float2 ze = make_float2(0.5f * (z0.x + z1.x), 0.5f * (z0.y - z1.y));
      float2 zo = make_float2(0.5f * (z0.y + z1.y), 0.5f * (z1.x - z0.x));
      float2 T = tw[p];
      float2 tz = make_float2(zo.x * T.x - zo.y * T.y,
                              zo.x * T.y + zo.y * T.x);
      Zt[p] = make_float2(ze.x + tz.x, ze.y + tz.y);
      float2 yb = make_float2(ze.x - tz.x, tz.y - ze.y);  // conj(ze-tz)
      if (p == 0) y256[t] = yb.x;         // Y[256] = ReZ0 - ImZ0 (imag==0)
      else Zt[256 - p] = yb;
    }
  }
  __syncthreads();

  // ---- fused mag/phase + direct coalesced store (16 contiguous t / f) ----
  const long plane = (long)BATCH * NF * NT;
  const long pb = (long)b * NF * NT;
  for (int r = 0; r < 17; ++r) {
    int tau = r * 256 + tid;
    if (tau < NF * FPB) {
      int t = tau & 15;
      int ff = tau >> 4;                  // 0..256
      int tt = t0 + t;
      if (tt < NT) {
        float rr, ii;
        if (ff < 256) {
          float2 v = Z[t * ZSTR + ff];
          rr = v.x; ii = v.y;
        } else {
          rr = y256[t]; ii = 0.f;
        }
        // Branch-cut / near-origin patch: recompute with v5's EXACT
        // sequential-k fmaf order (bit-identical to the kernel that passed).
        float ie = ii + EPSF, re = rr + EPSF;
        if (fabsf(ie) < TAU && re < TAU) {
          const float* wr = w + (long)ff * KLEN;
          const float* wi = w + (long)(257 + ff) * KLEN;
          const float* xf = &xs[t * INC];
          float r2 = 0.f, i2 = 0.f;
          for (int k = 0; k < KLEN; ++k) {   // sequential, k ascending
            float xv = xf[k];
            r2 = fmaf(wr[k], xv, r2);
            i2 = fmaf(wi[k], xv, i2);
          }
          rr = r2; ii = i2;
        }
        long o = pb + (long)ff * NT + tt;
        out[o] = sqrtf(fmaxf(rr * rr + ii * ii, EPSF));
        out[o + plane] = atan2f(ii + EPSF, rr + EPSF);
      }
    }
  }
}

extern "C" void kernel_launch(void* const* d_in, const int* in_sizes, int n_in,
                              void* d_out, int out_size, void* d_ws, size_t ws_size,
                              hipStream_t stream) {
  const float* x = (const float*)d_in[0];   // (16, 160000) fp32
  const float* w = (const float*)d_in[1];   // (514, 1, 400) fp32
  float* out = (float*)d_out;

  dim3 grid(NTB, BATCH);                    // 101 x 16 = 1616 blocks
  stft_fft<<<grid, dim3(256), 0, stream>>>(x, w, out);
}

// Round 4
// 156.012 us; speedup vs baseline: 1.5673x; 1.1305x over previous
//
#include <hip/hip_runtime.h>
#include <math.h>

// R4: register-resident four-step FFT (256 = 16x16) — kills the barrier/LDS
// latency bound. R3 counters: VALUBusy 30%, HBM 8.7%, Occupancy 15% ->
// latency-bound: 8 LDS radix-2 stages x tiny work between 12 barriers,
// ~120cy LDS latency, 5.06M bank-conflict cycles (short-stride s=0/1).
// New structure per frame (16 workers x 16 points each):
//   load z[16*n1+w] straight from xs (window fused) -> 16-pt DIF FFT in
//   REGISTERS (compile-time twiddles, no LDS/sync) -> x tw256[w*k1] ->
//   ONE LDS transpose -> second 16-pt register FFT -> write spectrum ->
//   rFFT unpack FUSED into mag/phase epilogue (pairs (p,256-p) read once,
//   both f-rows stored straight to global; no in-place pass, no obuf).
// Barriers 12 -> 3. All LDS patterns <=2-way (free, m136).
// Math: Z[16k2+k1] = sum_{n2} w256^{n2 k1} w16^{n2 k2} F1[n2][k1],
//       F1[n2][k1] = sum_{n1} z[16n1+n2] w16^{n1 k1}   (DIF -> brev4 order).
// Branch-cut patch kept BIT-IDENTICAL to R3 (sequential-k fmaf, the rounding
// class that agrees with the np reference; only recomputes |i+e|,r+e < TAU).

#define BATCH 16
#define NSAMP 160000
#define NF 257
#define NT 1603
#define KLEN 400
#define INC 100
#define PADL 300
#define EPSF 1.1920928955078125e-7f
#define TAU 1e-2f

#define FPB 16                            // frames per block
#define ZSTR 258                          // complex stride per frame (bank stagger)
#define XSPAN ((FPB - 1) * INC + KLEN)    // 1900
#define NTB ((NT + FPB - 1) / FPB)        // 101

__device__ __forceinline__ float2 cmul(float2 a, float2 b) {
  return make_float2(a.x * b.x - a.y * b.y, a.x * b.y + a.y * b.x);
}

// 16-point DIF FFT in registers; output a[r] = F[brev4(r)].
__device__ __forceinline__ void fft16_dif(float2* a) {
  const float C1 = 0.92387953251128674f;   // cos(pi/8)
  const float S1 = 0.38268343236508978f;   // sin(pi/8)
  const float R2 = 0.70710678118654752f;   // sqrt(2)/2
  {                                        // span 8, tw = w16^j
    const float2 W[8] = {{1.f, 0.f},  {C1, -S1},  {R2, -R2},  {S1, -C1},
                         {0.f, -1.f}, {-S1, -C1}, {-R2, -R2}, {-C1, -S1}};
    #pragma unroll
    for (int j = 0; j < 8; ++j) {
      float2 u = a[j], v = a[j + 8];
      a[j] = make_float2(u.x + v.x, u.y + v.y);
      float2 d = make_float2(u.x - v.x, u.y - v.y);
      a[j + 8] = cmul(d, W[j]);            // j=0/4 fold to copy / (y,-x)
    }
  }
  {                                        // span 4, tw = w8^j
    const float2 W[4] = {{1.f, 0.f}, {R2, -R2}, {0.f, -1.f}, {-R2, -R2}};
    #pragma unroll
    for (int h = 0; h < 16; h += 8)
      #pragma unroll
      for (int j = 0; j < 4; ++j) {
        float2 u = a[h + j], v = a[h + j + 4];
        a[h + j] = make_float2(u.x + v.x, u.y + v.y);
        float2 d = make_float2(u.x - v.x, u.y - v.y);
        a[h + j + 4] = cmul(d, W[j]);
      }
  }
  #pragma unroll
  for (int q = 0; q < 16; q += 4) {        // span 2, tw = {1, -i}
    float2 u0 = a[q], v0 = a[q + 2];
    a[q] = make_float2(u0.x + v0.x, u0.y + v0.y);
    a[q + 2] = make_float2(u0.x - v0.x, u0.y - v0.y);
    float2 u1 = a[q + 1], v1 = a[q + 3];
    a[q + 1] = make_float2(u1.x + v1.x, u1.y + v1.y);
    float2 d = make_float2(u1.x - v1.x, u1.y - v1.y);
    a[q + 3] = make_float2(d.y, -d.x);     // *(-i)
  }
  #pragma unroll
  for (int q = 0; q < 16; q += 2) {        // span 1
    float2 u = a[q], v = a[q + 1];
    a[q] = make_float2(u.x + v.x, u.y + v.y);
    a[q + 1] = make_float2(u.x - v.x, u.y - v.y);
  }
}

// mag/phase emit with the R3 branch-cut exactness patch (sequential-k fmaf).
__device__ __forceinline__ void emit_fp(float rr, float ii, int ff,
                                        const float* __restrict__ w,
                                        const float* xf,
                                        float* __restrict__ out,
                                        long o, long plane) {
  float ie = ii + EPSF, re = rr + EPSF;
  if (fabsf(ie) < TAU && re < TAU) {       // cold path, ~few pts/block
    const float* wr = w + (long)ff * KLEN;
    const float* wi = w + (long)(257 + ff) * KLEN;
    float r2 = 0.f, i2 = 0.f;
    for (int k = 0; k < KLEN; ++k) {       // sequential, k ascending (v5 order)
      float xv = xf[k];
      r2 = fmaf(wr[k], xv, r2);
      i2 = fmaf(wi[k], xv, i2);
    }
    rr = r2; ii = i2;
  }
  out[o] = sqrtf(fmaxf(rr * rr + ii * ii, EPSF));
  out[o + plane] = atan2f(ii + EPSF, rr + EPSF);
}

__global__ __launch_bounds__(256, 3)
void stft_fft4(const float* __restrict__ x, const float* __restrict__ w,
               float* __restrict__ out) {
  __shared__ float2 Z[FPB * ZSTR];          // 33024 B spectrum / transpose buf
  __shared__ float2 tw[132];                // e^{-2pi i p/512}, p<=128 (unpack)
  __shared__ float2 tw256[256];             // e^{-2pi i j/256} (inter-stage)
  __shared__ __align__(16) float xs[XSPAN]; // zero-padded input window
  __shared__ __align__(16) float win[KLEN]; // = W row 0 exactly

  const int tid = threadIdx.x;
  const int t0 = blockIdx.x * FPB;
  const int b = blockIdx.y;
  const int tl = tid & 15;                  // frame
  const int th = tid >> 4;                  // worker: n2 (phase1) = k1 (phase2)

  // ---- stage xs (vectorized, zero-padded), window, twiddle tables ----
  const long xb = (long)b * NSAMP;
  const int base = t0 * INC - PADL;
  for (int r = 0; r < 2; ++r) {
    int i4 = r * 256 + tid;
    if (4 * i4 < XSPAN) {
      int g = base + 4 * i4;
      float4 v;
      if (g >= 0 && g + 3 < NSAMP) {
        v = *(const float4*)(x + xb + g);
      } else {
        v.x = (g + 0 >= 0 && g + 0 < NSAMP) ? x[xb + g + 0] : 0.f;
        v.y = (g + 1 >= 0 && g + 1 < NSAMP) ? x[xb + g + 1] : 0.f;
        v.z = (g + 2 >= 0 && g + 2 < NSAMP) ? x[xb + g + 2] : 0.f;
        v.w = (g + 3 >= 0 && g + 3 < NSAMP) ? x[xb + g + 3] : 0.f;
      }
      *(float4*)&xs[4 * i4] = v;
    }
  }
  if (tid < KLEN / 4) {                     // W[0][k] = fp32(hamming) exactly
    *(float4*)&win[4 * tid] = *(const float4*)(w + 4 * tid);
  }
  {
    double a = (double)tid * (6.283185307179586476925286766559 / 256.0);
    tw256[tid] = make_float2((float)cos(a), (float)(-sin(a)));
  }
  if (tid < 132) {
    double a = (double)tid * (6.283185307179586476925286766559 / 512.0);
    tw[tid] = make_float2((float)cos(a), (float)(-sin(a)));
  }
  __syncthreads();

  // ---- phase 1: windowed load z[16*n1+th] -> register FFT over n1 ----
  float2 a[16];
  const float* xf = &xs[tl * INC];
  #pragma unroll
  for (int n1 = 0; n1 < 12; ++n1) {         // n = 32*n1+2*th <= 382 < 400
    int n = 32 * n1 + 2 * th;
    float2 xv = *(const float2*)&xf[n];
    float2 wv = *(const float2*)&win[n];
    a[n1] = make_float2(xv.x * wv.x, xv.y * wv.y);
  }
  {
    int n = 384 + 2 * th;                   // n1 = 12: valid iff th <= 7
    if (n < KLEN) {
      float2 xv = *(const float2*)&xf[n];
      float2 wv = *(const float2*)&win[n];
      a[12] = make_float2(xv.x * wv.x, xv.y * wv.y);
    } else {
      a[12] = make_float2(0.f, 0.f);
    }
  }
  a[13] = a[14] = a[15] = make_float2(0.f, 0.f);   // y[n]=0, n>=416

  fft16_dif(a);                             // a[r] = F1[th][brev4(r)]

  static const int BR[16] = {0, 8, 4, 12, 2, 10, 6, 14,
                             1, 9, 5, 13, 3, 11, 7, 15};
  float2* Zf = Z + tl * ZSTR;
  #pragma unroll
  for (int r = 0; r < 16; ++r) {            // x w256^{th*k1}, transpose-store
    const int k1 = BR[r];
    float2 v = (k1 == 0) ? a[r] : cmul(a[r], tw256[th * k1]);
    Zf[th * 16 + k1] = v;                   // banks (4f+2k1): 2-way, free
  }
  __syncthreads();

  // ---- phase 2: column read (private per thread) -> register FFT over n2 ----
  float2 g[16];
  #pragma unroll
  for (int n2 = 0; n2 < 16; ++n2) g[n2] = Zf[n2 * 16 + th];
  fft16_dif(g);                             // g[r] = Z[16*brev4(r) + th]
  #pragma unroll
  for (int r = 0; r < 16; ++r) {
    const int k2 = BR[r];
    Zf[16 * k2 + th] = g[r];                // natural-order spectrum
  }
  __syncthreads();

  // ---- fused rFFT-unpack + mag/phase + coalesced store ----
  // Ze=(Z0+conj Z1)/2, Zo=(Z0-conj Z1)/(2i), T=tw[p]:
  // Y[p]=Ze+T*Zo ; Y[256-p]=conj(Ze-T*Zo).
  const long plane = (long)BATCH * NF * NT;
  const long pb = (long)b * NF * NT;
  for (int r = 0; r < 9; ++r) {
    int tau = r * 256 + tid;
    if (tau < FPB * 129) {
      int t = tau & 15;
      int p = tau >> 4;                     // 0..128
      float2* Zt = Z + t * ZSTR;
      float2 z0 = Zt[p];
      float2 z1 = Zt[(256 - p) & 255];
      float2 ze = make_float2(0.5f * (z0.x + z1.x), 0.5f * (z0.y - z1.y));
      float2 zo = make_float2(0.5f * (z0.y + z1.y), 0.5f * (z1.x - z0.x));
      float2 T = tw[p];
      float2 tz = cmul(zo, T);
      float2 ya = make_float2(ze.x + tz.x, ze.y + tz.y);          // Y[p]
      float2 yb = make_float2(ze.x - tz.x, tz.y - ze.y);          // Y[256-p]
      int tt = t0 + t;
      if (tt < NT) {
        const float* xfr = &xs[t * INC];
        emit_fp(ya.x, ya.y, p, w, xfr, out, pb + (long)p * NT + tt, plane);
        if (p == 0) {
          emit_fp(yb.x, 0.f, 256, w, xfr, out, pb + (long)256 * NT + tt, plane);
        } else {
          emit_fp(yb.x, yb.y, 256 - p, w, xfr, out,
                  pb + (long)(256 - p) * NT + tt, plane);
        }
      }
    }
  }
}

extern "C" void kernel_launch(void* const* d_in, const int* in_sizes, int n_in,
                              void* d_out, int out_size, void* d_ws, size_t ws_size,
                              hipStream_t stream) {
  const float* x = (const float*)d_in[0];   // (16, 160000) fp32
  const float* w = (const float*)d_in[1];   // (514, 1, 400) fp32
  float* out = (float*)d_out;

  dim3 grid(NTB, BATCH);                    // 101 x 16 = 1616 blocks
  stft_fft4<<<grid, dim3(256), 0, stream>>>(x, w, out);
}